// Round 2
// baseline (151.759 us; speedup 1.0000x reference)
//
#include <hip/hip_runtime.h>

// GAT forward: B=8, N=1024, IN_F=OUT_F=128, H=4, HD=32, LeakyReLU(0.2), softmax over j.
//   K1 (proj):  h = x@W; s[bh,n]=<h,a_src>, d-terms packed as dAB[bh,n]={d, e^d, e^{0.2d}}.
//               x-row values are wave-uniform -> SGPR operands, no LDS at all.
//   K2 (attn):  w_ij = (s_i+d_j>=0) ? e^{s_i}e^{d_j} : e^{0.2 s_i}e^{0.2 d_j}.
//               h[j,:] is wave-uniform -> s_load into SGPRs; thread owns one i-row,
//               32 accumulators; inner loop = 6 VALU + 32 v_fmac, no LDS/VMEM.
//   K3 (combine): out = sum_jc acc / sum_jc l in (b,i,h,dd) layout.

constexpr int CB  = 8;
constexpr int CN  = 1024;
constexpr int CF  = 128;
constexpr int CH  = 4;
constexpr int CHD = 32;
constexpr int CBH = CB * CH;        // 32
constexpr int CROWS = CB * CN;      // 8192
constexpr int CBHN = CBH * CN;      // 32768

// ---------------- Kernel 1: projection + attention dots ----------------
// 1024 blocks x 128 threads; block owns 8 rows, thread owns one output col.
__global__ __launch_bounds__(128) void proj_kernel(
    const float* __restrict__ x, const float* __restrict__ W,
    const float* __restrict__ a_src, const float* __restrict__ a_dst,
    float* __restrict__ h_ws, float* __restrict__ sarr, float4* __restrict__ dAB)
{
    const int tid  = threadIdx.x;
    const int row0 = blockIdx.x * 8;
    const int col  = tid;
    const float4* x4 = (const float4*)x + (size_t)row0 * 32;   // uniform base

    float acc[8] = {0.f,0.f,0.f,0.f,0.f,0.f,0.f,0.f};
    for (int k4 = 0; k4 < 32; ++k4) {
        const float w0 = W[(k4 * 4 + 0) * CF + col];
        const float w1 = W[(k4 * 4 + 1) * CF + col];
        const float w2 = W[(k4 * 4 + 2) * CF + col];
        const float w3 = W[(k4 * 4 + 3) * CF + col];
        #pragma unroll
        for (int r = 0; r < 8; ++r) {
            const float4 xv = x4[r * 32 + k4];   // wave-uniform -> SGPRs
            acc[r] += xv.x * w0 + xv.y * w1 + xv.z * w2 + xv.w * w3;
        }
    }

    const int head = col >> 5, dd = col & 31;
    const float as = a_src[col];   // a_src[head][dd] == a_src[col]
    const float ad = a_dst[col];
    #pragma unroll
    for (int r = 0; r < 8; ++r) {
        const int row = row0 + r, b = row >> 10, n = row & 1023;
        const int bh = b * CH + head;
        h_ws[(size_t)(bh * CN + n) * CHD + dd] = acc[r];
        float ps = acc[r] * as, pd = acc[r] * ad;
        // butterfly sum over the 32 lanes of this head (xor bits 0..4 stay in-group)
        #pragma unroll
        for (int m = 16; m >= 1; m >>= 1) {
            ps += __shfl_xor(ps, m);
            pd += __shfl_xor(pd, m);
        }
        if (dd == 0) {
            sarr[bh * CN + n] = ps;
            dAB[bh * CN + n]  = make_float4(pd, __expf(pd), __expf(0.2f * pd), 0.f);
        }
    }
}

// ---------------- Kernel 2: attention partial sums ----------------
// grid = CBH * 4 * NJ blocks x 256 threads. Thread owns row i = it*256+tid (full 32 dds),
// iterates j over its chunk; h[j,:] and dAB[j] are wave-uniform scalar loads.
__global__ __launch_bounds__(256) void attn_kernel(
    const float4* __restrict__ h4, const float* __restrict__ sarr,
    const float4* __restrict__ dAB, float* __restrict__ pacc,
    float* __restrict__ pl, float* __restrict__ out, int NJ, int direct)
{
    int idx = blockIdx.x;
    const int jc = idx % NJ; idx /= NJ;
    const int it = idx & 3;  const int bh = idx >> 2;
    const int base = bh * CN;
    const int JT = CN / NJ;
    const int i = it * 256 + threadIdx.x;

    const float s  = sarr[base + i];
    const float c1 = __expf(s), c2 = __expf(0.2f * s);

    float acc[32];
    #pragma unroll
    for (int q = 0; q < 32; ++q) acc[q] = 0.f;
    float lacc = 0.f;

    const float4* __restrict__ hrow = h4 + (size_t)(base + jc * JT) * 8;
    const float4* __restrict__ dab  = dAB + base + jc * JT;

    #pragma unroll 2
    for (int j = 0; j < JT; ++j) {
        const float4 q = dab[j];                    // uniform: {d, e^d, e^{0.2d}}
        const float t = s + q.x;
        const float w = (t >= 0.f) ? c1 * q.y : c2 * q.z;
        lacc += w;
        #pragma unroll
        for (int p = 0; p < 8; ++p) {
            const float4 hv = hrow[j * 8 + p];      // uniform -> SGPRs
            acc[p*4+0] += w * hv.x; acc[p*4+1] += w * hv.y;
            acc[p*4+2] += w * hv.z; acc[p*4+3] += w * hv.w;
        }
    }

    const int irow = base + i;
    if (direct) {
        const int b = bh >> 2, hh = bh & 3;
        const float inv = 1.0f / lacc;
        float4* o = (float4*)(out + (size_t)(b * CN + i) * CF + hh * 32);
        #pragma unroll
        for (int p = 0; p < 8; ++p)
            o[p] = make_float4(acc[p*4]*inv, acc[p*4+1]*inv, acc[p*4+2]*inv, acc[p*4+3]*inv);
    } else {
        float4* pa = (float4*)(pacc + ((size_t)jc * CBHN + irow) * 32);
        #pragma unroll
        for (int p = 0; p < 8; ++p)
            pa[p] = make_float4(acc[p*4], acc[p*4+1], acc[p*4+2], acc[p*4+3]);
        pl[(size_t)jc * CBHN + irow] = lacc;
    }
}

// ---------------- Kernel 3: combine j-chunks, divide, write out ----------------
__global__ __launch_bounds__(256) void combine_kernel(
    const float* __restrict__ pacc, const float* __restrict__ pl,
    float* __restrict__ out, int NJ)
{
    const int idx = blockIdx.x * 256 + threadIdx.x;   // < CBHN*32
    const int row = idx >> 5, dd = idx & 31;
    float a = 0.f, l = 0.f;
    for (int jc = 0; jc < NJ; ++jc) {
        a += pacc[((size_t)jc * CBHN + row) * 32 + dd];
        l += pl[(size_t)jc * CBHN + row];
    }
    const int b = row >> 12, rem = row & 4095, hh = rem >> 10, i = rem & 1023;
    out[(size_t)(b * CN + i) * CF + hh * 32 + dd] = a / l;
}

extern "C" void kernel_launch(void* const* d_in, const int* in_sizes, int n_in,
                              void* d_out, int out_size, void* d_ws, size_t ws_size,
                              hipStream_t stream) {
    const float* x     = (const float*)d_in[0];
    const float* W     = (const float*)d_in[1];
    const float* a_src = (const float*)d_in[2];
    const float* a_dst = (const float*)d_in[3];
    float* out = (float*)d_out;

    char* ws = (char*)d_ws;
    size_t off = 0;
    float*  h_ws = (float*)(ws + off); off += (size_t)CROWS * CF * 4;   // 4 MB
    float*  sarr = (float*)(ws + off); off += (size_t)CBHN * 4;         // 128 KB
    float4* dAB  = (float4*)(ws + off); off += (size_t)CBHN * 16;       // 512 KB

    // pick largest NJ whose partial buffers fit the workspace
    int NJ = 8;
    float *pacc = nullptr, *pl = nullptr;
    for (; NJ >= 2; NJ >>= 1) {
        size_t need_pacc = (size_t)NJ * CBHN * 32 * 4;
        size_t need_pl   = (size_t)NJ * CBHN * 4;
        if (off + need_pacc + need_pl <= ws_size) {
            pacc = (float*)(ws + off);
            pl   = (float*)(ws + off + need_pacc);
            break;
        }
    }
    if (NJ < 2) NJ = 1;
    const int direct = (NJ == 1) ? 1 : 0;

    proj_kernel<<<CROWS / 8, 128, 0, stream>>>(x, W, a_src, a_dst, h_ws, sarr, dAB);

    attn_kernel<<<CBH * 4 * NJ, 256, 0, stream>>>(
        (const float4*)h_ws, sarr, dAB, pacc, pl, out, NJ, direct);

    if (!direct) {
        combine_kernel<<<(CBHN * 32) / 256, 256, 0, stream>>>(pacc, pl, out, NJ);
    }
}

// Round 3
// 140.348 us; speedup vs baseline: 1.0813x; 1.0813x over previous
//
#include <hip/hip_runtime.h>

// GAT forward, O(N*HD) algorithm via sorted-prefix decomposition.
// B=8, N=1024, F=128, H=4, HD=32, LeakyReLU(0.2), softmax over j.
//
// score(i,j) = s_i + d_j ; negative iff d_j < -s_i.
// Sort j by d_j per (b,h). Then:
//   out[i,:] = (c2_i * PB_h[k_i] + c1_i * SufA_h[k_i])
//            / (c2_i * PB_1[k_i] + c1_i * SufA_1[k_i])
// with k_i = lower_bound(sorted d, -s_i),
//   PB  = exclusive prefix sums of e^{0.2 d}*h  (negative branch),
//   SufA= inclusive suffix  sums of e^{d}*h     (positive branch),
//   c1 = e^{s_i}, c2 = e^{0.2 s_i}.
// Pipeline: proj -> bitonic sort -> chunked scans -> chunk offsets -> gather/out.

constexpr int CB  = 8;
constexpr int CN  = 1024;
constexpr int CF  = 128;
constexpr int CH  = 4;
constexpr int CHD = 32;
constexpr int CBH = CB * CH;        // 32
constexpr int CROWS = CB * CN;      // 8192
constexpr int CHK = 64;             // scan chunk length
constexpr int NCH = CN / CHK;       // 16 chunks
constexpr int TROWS = CN + 1;       // 1025 table rows (row 1024 = zeros)

// ---------------- K1: projection + attention dots ----------------
// 2048 blocks x 128 threads; block owns 4 rows, thread owns one output col.
// x-row values are wave-uniform -> scalar loads; W loads coalesced vector.
__global__ __launch_bounds__(128) void proj_kernel(
    const float* __restrict__ x, const float* __restrict__ W,
    const float* __restrict__ a_src, const float* __restrict__ a_dst,
    float* __restrict__ h_ws, float* __restrict__ sarr, float* __restrict__ darr)
{
    const int tid  = threadIdx.x;
    const int row0 = blockIdx.x * 4;
    const int col  = tid;
    const float4* x4 = (const float4*)x + (size_t)row0 * 32;   // uniform base

    float acc[4] = {0.f, 0.f, 0.f, 0.f};
    for (int k4 = 0; k4 < 32; ++k4) {
        const float w0 = W[(k4 * 4 + 0) * CF + col];
        const float w1 = W[(k4 * 4 + 1) * CF + col];
        const float w2 = W[(k4 * 4 + 2) * CF + col];
        const float w3 = W[(k4 * 4 + 3) * CF + col];
        #pragma unroll
        for (int r = 0; r < 4; ++r) {
            const float4 xv = x4[r * 32 + k4];   // wave-uniform -> SGPRs
            acc[r] += xv.x * w0 + xv.y * w1 + xv.z * w2 + xv.w * w3;
        }
    }

    const int head = col >> 5, dd = col & 31;
    const float as = a_src[col];
    const float ad = a_dst[col];
    #pragma unroll
    for (int r = 0; r < 4; ++r) {
        const int row = row0 + r, b = row >> 10, n = row & 1023;
        const int bh = b * CH + head;
        h_ws[(size_t)(bh * CN + n) * CHD + dd] = acc[r];
        float ps = acc[r] * as, pd = acc[r] * ad;
        #pragma unroll
        for (int m = 16; m >= 1; m >>= 1) {       // butterfly within 32-lane head group
            ps += __shfl_xor(ps, m);
            pd += __shfl_xor(pd, m);
        }
        if (dd == 0) {
            sarr[bh * CN + n] = ps;
            darr[bh * CN + n] = pd;
        }
    }
}

// ---------------- K2: bitonic sort of d per bh (ascending), with permutation ----
__global__ __launch_bounds__(256) void sort_kernel(
    const float* __restrict__ darr, float* __restrict__ dsrt, int* __restrict__ perm)
{
    __shared__ float dk[CN];
    __shared__ int   pj[CN];
    const int bh = blockIdx.x, tid = threadIdx.x;
    for (int t = tid; t < CN; t += 256) { dk[t] = darr[bh * CN + t]; pj[t] = t; }
    __syncthreads();
    for (int k = 2; k <= CN; k <<= 1) {
        for (int j = k >> 1; j > 0; j >>= 1) {
            #pragma unroll
            for (int m = 0; m < 4; ++m) {
                const int i = tid + m * 256, ixj = i ^ j;
                if (ixj > i) {
                    const bool asc = ((i & k) == 0);
                    const float a = dk[i], b = dk[ixj];
                    if ((a > b) == asc) {
                        dk[i] = b; dk[ixj] = a;
                        const int t0 = pj[i]; pj[i] = pj[ixj]; pj[ixj] = t0;
                    }
                }
            }
            __syncthreads();
        }
    }
    for (int t = tid; t < CN; t += 256) { dsrt[bh * CN + t] = dk[t]; perm[bh * CN + t] = pj[t]; }
}

// ---------------- K3a: chunk-local scans ----------------
// grid = 32 bh x 16 chunks, 64 threads (1 wave). Lanes 0..31: forward exclusive
// prefix of e^{0.2 d}*h (dim dd); lanes 32..63: backward inclusive suffix of
// e^{d}*h. Chunk totals out for K3b.
__global__ __launch_bounds__(64) void scan_kernel(
    const float* __restrict__ h_ws, const float* __restrict__ dsrt,
    const int* __restrict__ perm, float* __restrict__ tbl, float* __restrict__ tblS,
    float* __restrict__ ctot, float* __restrict__ ctotS)
{
    const int bh = blockIdx.x >> 4, chunk = blockIdx.x & 15;
    const int lane = threadIdx.x, half = lane >> 5, dd = lane & 31;
    const int base = chunk * CHK;
    float acc = 0.f, accS = 0.f;
    for (int t = 0; t < CHK; ++t) {
        const int p = base + (half ? (CHK - 1 - t) : t);
        const float d = dsrt[bh * CN + p];
        const float coef = half ? __expf(d) : __expf(0.2f * d);
        const int j = perm[bh * CN + p];
        const float hv = h_ws[(size_t)(bh * CN + j) * CHD + dd];
        const float val = coef * hv;
        const size_t trow = (size_t)(bh * TROWS + p) * 64;
        if (half == 0) {
            tbl[trow + dd] = acc;                       // exclusive prefix
            acc += val;
            if (lane == 0) tblS[(bh * TROWS + p) * 2 + 0] = accS;
            accS += coef;
        } else {
            acc += val;
            tbl[trow + 32 + dd] = acc;                  // inclusive suffix
            accS += coef;
            if (lane == 32) tblS[(bh * TROWS + p) * 2 + 1] = accS;
        }
    }
    ctot[(bh * NCH + chunk) * 64 + lane] = acc;
    if (lane == 0)  ctotS[(bh * NCH + chunk) * 2 + 0] = accS;
    if (lane == 32) ctotS[(bh * NCH + chunk) * 2 + 1] = accS;
}

// ---------------- K3b: scan chunk totals -> per-chunk offsets; zero row 1024 ----
// For k in chunk c: PB(k) = tbl_local + offs[c] (chunks before c);
//                   SufA(k) = tbl_local + offs[c] (chunks after c).
// offs has NCH+1 rows; row NCH serves k==1024 (PB=grand total, SufA=0).
__global__ __launch_bounds__(64) void offs_kernel(
    const float* __restrict__ ctot, const float* __restrict__ ctotS,
    float* __restrict__ offs, float* __restrict__ offsS,
    float* __restrict__ tbl, float* __restrict__ tblS)
{
    const int bh = blockIdx.x, lane = threadIdx.x, half = lane >> 5;
    float run = 0.f;
    for (int ci = 0; ci < NCH; ++ci) {
        const int c = half ? (NCH - 1 - ci) : ci;
        const float t = ctot[(bh * NCH + c) * 64 + lane];
        offs[(bh * (NCH + 1) + c) * 64 + lane] = run;
        run += t;
    }
    offs[(bh * (NCH + 1) + NCH) * 64 + lane] = half ? 0.f : run;
    if (lane == 0 || lane == 32) {
        float runS = 0.f;
        for (int ci = 0; ci < NCH; ++ci) {
            const int c = half ? (NCH - 1 - ci) : ci;
            const float t = ctotS[(bh * NCH + c) * 2 + half];
            offsS[(bh * (NCH + 1) + c) * 2 + half] = runS;
            runS += t;
        }
        offsS[(bh * (NCH + 1) + NCH) * 2 + half] = half ? 0.f : runS;
    }
    // zero virtual table row k == 1024 so K4 needs no special case
    tbl[(size_t)(bh * TROWS + CN) * 64 + lane] = 0.f;
    if (lane < 2) tblS[(bh * TROWS + CN) * 2 + lane] = 0.f;
}

// ---------------- K4: per-row binary search + gather + combine ----------------
__global__ __launch_bounds__(256) void out_kernel(
    const float* __restrict__ sarr, const float* __restrict__ dsrt,
    const float* __restrict__ tbl, const float* __restrict__ tblS,
    const float* __restrict__ offs, const float* __restrict__ offsS,
    float* __restrict__ out)
{
    __shared__ float dsS[CN];
    const int bh = blockIdx.x >> 2, it = blockIdx.x & 3, tid = threadIdx.x;
    for (int t = tid; t < CN; t += 256) dsS[t] = dsrt[bh * CN + t];
    __syncthreads();

    const int i = it * 256 + tid;
    const float s = sarr[bh * CN + i];
    const float c1 = __expf(s), c2 = __expf(0.2f * s), thr = -s;

    int lo = 0, hi = CN;                       // lower_bound: count of d < -s
    while (lo < hi) { const int mid = (lo + hi) >> 1; if (dsS[mid] < thr) lo = mid + 1; else hi = mid; }
    const int k = lo, c = k >> 6;              // chunk index, 0..16 (k==1024 -> 16)

    const float4* trow = (const float4*)(tbl  + (size_t)(bh * TROWS + k) * 64);
    const float4* orow = (const float4*)(offs + (size_t)(bh * (NCH + 1) + c) * 64);
    const float PBs = tblS[(bh * TROWS + k) * 2 + 0] + offsS[(bh * (NCH + 1) + c) * 2 + 0];
    const float Sfs = tblS[(bh * TROWS + k) * 2 + 1] + offsS[(bh * (NCH + 1) + c) * 2 + 1];
    const float inv = 1.0f / (c2 * PBs + c1 * Sfs);

    const int b = bh >> 2, hh = bh & 3;
    float4* o = (float4*)(out + (size_t)(b * CN + i) * CF + hh * 32);
    #pragma unroll
    for (int q = 0; q < 8; ++q) {
        const float4 pb = trow[q],     sf = trow[8 + q];
        const float4 ob = orow[q],     os = orow[8 + q];
        float4 r;
        r.x = (c2 * (pb.x + ob.x) + c1 * (sf.x + os.x)) * inv;
        r.y = (c2 * (pb.y + ob.y) + c1 * (sf.y + os.y)) * inv;
        r.z = (c2 * (pb.z + ob.z) + c1 * (sf.z + os.z)) * inv;
        r.w = (c2 * (pb.w + ob.w) + c1 * (sf.w + os.w)) * inv;
        o[q] = r;
    }
}

extern "C" void kernel_launch(void* const* d_in, const int* in_sizes, int n_in,
                              void* d_out, int out_size, void* d_ws, size_t ws_size,
                              hipStream_t stream) {
    const float* x     = (const float*)d_in[0];
    const float* W     = (const float*)d_in[1];
    const float* a_src = (const float*)d_in[2];
    const float* a_dst = (const float*)d_in[3];
    float* out = (float*)d_out;

    char* ws = (char*)d_ws;
    size_t off = 0;
    float* h_ws  = (float*)(ws + off); off += (size_t)CROWS * CF * 4;              // 4 MB
    float* sarr  = (float*)(ws + off); off += (size_t)CBH * CN * 4;                // 128 KB
    float* darr  = (float*)(ws + off); off += (size_t)CBH * CN * 4;                // 128 KB
    float* dsrt  = (float*)(ws + off); off += (size_t)CBH * CN * 4;                // 128 KB
    int*   perm  = (int*)  (ws + off); off += (size_t)CBH * CN * 4;                // 128 KB
    float* tbl   = (float*)(ws + off); off += (size_t)CBH * TROWS * 64 * 4;        // 8.4 MB
    float* tblS  = (float*)(ws + off); off += (size_t)CBH * TROWS * 2 * 4;         // 262 KB
    float* ctot  = (float*)(ws + off); off += (size_t)CBH * NCH * 64 * 4;          // 131 KB
    float* ctotS = (float*)(ws + off); off += (size_t)CBH * NCH * 2 * 4;           // 4 KB
    float* offsA = (float*)(ws + off); off += (size_t)CBH * (NCH + 1) * 64 * 4;    // 139 KB
    float* offsS = (float*)(ws + off); off += (size_t)CBH * (NCH + 1) * 2 * 4;     // 4.4 KB
    (void)ws_size;

    proj_kernel<<<CROWS / 4, 128, 0, stream>>>(x, W, a_src, a_dst, h_ws, sarr, darr);
    sort_kernel<<<CBH, 256, 0, stream>>>(darr, dsrt, perm);
    scan_kernel<<<CBH * NCH, 64, 0, stream>>>(h_ws, dsrt, perm, tbl, tblS, ctot, ctotS);
    offs_kernel<<<CBH, 64, 0, stream>>>(ctot, ctotS, offsA, offsS, tbl, tblS);
    out_kernel<<<CBH * 4, 256, 0, stream>>>(sarr, dsrt, tbl, tblS, offsA, offsS, out);
}

// Round 4
// 132.105 us; speedup vs baseline: 1.1488x; 1.0624x over previous
//
#include <hip/hip_runtime.h>

// GAT forward, O(N*HD) via sorted-prefix decomposition. B=8,N=1024,F=128,H=4,HD=32.
// score(i,j)=s_i+d_j; negative iff d_j < -s_i. Sort j by d_j per (b,h):
//   out[i,:] = (c2*PB[k_i] + c1*SufA[k_i]) / (c2*PBs[k_i] + c1*SufAs[k_i])
// PB: exclusive prefix of e^{0.2d}*h; SufA: inclusive suffix of e^{d}*h;
// k_i = lower_bound(dsrt, -s_i); c1=e^s, c2=e^{0.2s}.
// s,d computed exactly from x via vs[h]=W@a_src, vd[h]=W@a_dst (no h roundoff).

constexpr int CB  = 8;
constexpr int CN  = 1024;
constexpr int CF  = 128;
constexpr int CH  = 4;
constexpr int CHD = 32;
constexpr int CBH = CB * CH;        // 32
constexpr int CROWS = CB * CN;      // 8192
constexpr int CHK = 16;             // scan chunk length
constexpr int NCH = CN / CHK;       // 64 chunks
constexpr int TROWS = CN + 1;       // 1025 table rows (row 1024 = zeros)

// ---------------- K1: projection + exact s/d ----------------
// grid 128 blocks x 256 thr. Block tile: 64 rows x 128 cols. lane = row-in-tile,
// wave w owns head w (cols 32w..32w+31, 32 accs/lane). x staged in LDS with XOR
// swizzle -> per-lane ds_read_b128, conflict-free. W and vs/vd wave-uniform ->
// scalar loads / LDS broadcast.
__global__ __launch_bounds__(256) void proj_kernel(
    const float* __restrict__ x, const float* __restrict__ W,
    const float* __restrict__ a_src, const float* __restrict__ a_dst,
    float* __restrict__ h_ws, float* __restrict__ sarr, float* __restrict__ darr)
{
    __shared__ float4 xs4[64 * 32];     // 32 KB, swizzled
    __shared__ float  vs_lds[CH][CF];   // 2 KB
    __shared__ float  vd_lds[CH][CF];   // 2 KB

    const int tid  = threadIdx.x;
    const int row0 = blockIdx.x * 64;

    // stage x tile (coalesced read, swizzled write)
    const float4* x4 = (const float4*)x + (size_t)row0 * 32;
    #pragma unroll
    for (int m = 0; m < 8; ++m) {
        const int idx = m * 256 + tid;          // 0..2047
        const int r = idx >> 5, k4 = idx & 31;
        xs4[r * 32 + (k4 ^ (r & 7))] = x4[idx];
    }
    // vs/vd precompute: thread t<128 -> vs for f=t (4 heads); t>=128 -> vd for f=t-128
    {
        const int f = tid & 127;
        const float* av   = (tid >= 128) ? a_dst : a_src;
        const float* wrow = W + f * CF;
        #pragma unroll
        for (int h = 0; h < CH; ++h) {
            float s = 0.f;
            #pragma unroll 8
            for (int d = 0; d < CHD; ++d) s += wrow[h * 32 + d] * av[h * 32 + d];
            if (tid >= 128) vd_lds[h][f] = s; else vs_lds[h][f] = s;
        }
    }
    __syncthreads();

    const int lane = tid & 63, w = tid >> 6;    // lane = row, w = head
    float acc[32];
    #pragma unroll
    for (int c = 0; c < 32; ++c) acc[c] = 0.f;
    float sacc = 0.f, dacc = 0.f;

    for (int k4 = 0; k4 < 32; ++k4) {
        const float4 xv = xs4[lane * 32 + (k4 ^ (lane & 7))];   // per-lane b128
        const float xq[4] = {xv.x, xv.y, xv.z, xv.w};
        #pragma unroll
        for (int q = 0; q < 4; ++q) {
            const int k = k4 * 4 + q;
            const float4* wr4 = (const float4*)(W + (size_t)k * CF + w * 32); // uniform
            const float4 w0 = wr4[0], w1 = wr4[1], w2 = wr4[2], w3 = wr4[3];
            const float4 w4 = wr4[4], w5 = wr4[5], w6 = wr4[6], w7 = wr4[7];
            const float xk = xq[q];
            acc[ 0]+=xk*w0.x; acc[ 1]+=xk*w0.y; acc[ 2]+=xk*w0.z; acc[ 3]+=xk*w0.w;
            acc[ 4]+=xk*w1.x; acc[ 5]+=xk*w1.y; acc[ 6]+=xk*w1.z; acc[ 7]+=xk*w1.w;
            acc[ 8]+=xk*w2.x; acc[ 9]+=xk*w2.y; acc[10]+=xk*w2.z; acc[11]+=xk*w2.w;
            acc[12]+=xk*w3.x; acc[13]+=xk*w3.y; acc[14]+=xk*w3.z; acc[15]+=xk*w3.w;
            acc[16]+=xk*w4.x; acc[17]+=xk*w4.y; acc[18]+=xk*w4.z; acc[19]+=xk*w4.w;
            acc[20]+=xk*w5.x; acc[21]+=xk*w5.y; acc[22]+=xk*w5.z; acc[23]+=xk*w5.w;
            acc[24]+=xk*w6.x; acc[25]+=xk*w6.y; acc[26]+=xk*w6.z; acc[27]+=xk*w6.w;
            acc[28]+=xk*w7.x; acc[29]+=xk*w7.y; acc[30]+=xk*w7.z; acc[31]+=xk*w7.w;
            sacc += xk * vs_lds[w][k];           // uniform broadcast
            dacc += xk * vd_lds[w][k];
        }
    }

    const int row = row0 + lane, b = row >> 10, n = row & 1023;
    const int bh = b * CH + w;
    float4* hdst = (float4*)(h_ws + (size_t)(bh * CN + n) * CHD);
    #pragma unroll
    for (int p = 0; p < 8; ++p)
        hdst[p] = make_float4(acc[p*4], acc[p*4+1], acc[p*4+2], acc[p*4+3]);
    sarr[bh * CN + n] = sacc;
    darr[bh * CN + n] = dacc;
}

// ---------------- K2: hybrid bitonic sort (ascending d, with permutation) ----
// 32 blocks x 1024 thr; element per thread in registers; j<64 via shuffles,
// j>=64 via LDS. Lexicographic (d,perm) -> strict total order.
__global__ __launch_bounds__(1024) void sort_kernel(
    const float* __restrict__ darr, float* __restrict__ dsrt, int* __restrict__ perm)
{
    __shared__ float dk[CN];
    __shared__ int   pj[CN];
    const int bh = blockIdx.x, i = threadIdx.x;
    float d = darr[bh * CN + i];
    int   p = i;

    for (int k = 2; k <= CN; k <<= 1) {
        for (int j = k >> 1; j > 0; j >>= 1) {
            float pd; int pp;
            if (j >= 64) {
                dk[i] = d; pj[i] = p;
                __syncthreads();
                pd = dk[i ^ j]; pp = pj[i ^ j];
                __syncthreads();
            } else {
                pd = __shfl_xor(d, j);
                pp = __shfl_xor(p, j);
            }
            const bool up = ((i & k) == 0);
            const bool iAmLow = ((i & j) == 0);
            const bool mineGreater = (d > pd) || (d == pd && p > pp);
            if (mineGreater == (iAmLow == up)) { d = pd; p = pp; }
        }
    }
    dsrt[bh * CN + i] = d;
    perm[bh * CN + i] = p;
}

// ---------------- K3: chunk-local scans (CHK=16), gathers prefetched ----------
// grid = 32 bh x 64 chunks, 64 thr. Lanes 0..31: forward exclusive prefix of
// e^{0.2d}*h; lanes 32..63: backward inclusive suffix of e^{d}*h.
__global__ __launch_bounds__(64) void scan_kernel(
    const float* __restrict__ h_ws, const float* __restrict__ dsrt,
    const int* __restrict__ perm, float* __restrict__ tbl, float* __restrict__ tblS,
    float* __restrict__ ctot, float* __restrict__ ctotS)
{
    const int bh = blockIdx.x >> 6, chunk = blockIdx.x & 63;
    const int lane = threadIdx.x, half = lane >> 5, dd = lane & 31;
    const int base = chunk * CHK;

    // uniform chunk metadata
    const float4* dp = (const float4*)(dsrt + bh * CN + base);
    const int4*   pp = (const int4*)(perm + bh * CN + base);
    const float4 dv0 = dp[0], dv1 = dp[1], dv2 = dp[2], dv3 = dp[3];
    const int4   pv0 = pp[0], pv1 = pp[1], pv2 = pp[2], pv3 = pp[3];
    const float dvals[16] = {dv0.x,dv0.y,dv0.z,dv0.w, dv1.x,dv1.y,dv1.z,dv1.w,
                             dv2.x,dv2.y,dv2.z,dv2.w, dv3.x,dv3.y,dv3.z,dv3.w};
    const int   jv[16]    = {pv0.x,pv0.y,pv0.z,pv0.w, pv1.x,pv1.y,pv1.z,pv1.w,
                             pv2.x,pv2.y,pv2.z,pv2.w, pv3.x,pv3.y,pv3.z,pv3.w};

    float hv[16];
    #pragma unroll
    for (int u = 0; u < 16; ++u)               // 16 independent gathers in flight
        hv[u] = h_ws[(size_t)(bh * CN + jv[u]) * CHD + dd];
    float cf[16];
    const float alpha = half ? 1.0f : 0.2f;
    #pragma unroll
    for (int u = 0; u < 16; ++u) cf[u] = __expf(alpha * dvals[u]);

    float acc = 0.f, accS = 0.f;
    if (half == 0) {
        #pragma unroll
        for (int t = 0; t < 16; ++t) {
            const int pos = base + t;
            tbl[(size_t)(bh * TROWS + pos) * 64 + dd] = acc;        // exclusive
            if (lane == 0) tblS[(bh * TROWS + pos) * 2 + 0] = accS;
            acc  += cf[t] * hv[t];
            accS += cf[t];
        }
    } else {
        #pragma unroll
        for (int t = 0; t < 16; ++t) {
            const int u = 15 - t, pos = base + u;
            acc  += cf[u] * hv[u];
            accS += cf[u];
            tbl[(size_t)(bh * TROWS + pos) * 64 + 32 + dd] = acc;   // inclusive suffix
            if (lane == 32) tblS[(bh * TROWS + pos) * 2 + 1] = accS;
        }
    }
    ctot[(bh * NCH + chunk) * 64 + lane] = acc;
    if (lane == 0)  ctotS[(bh * NCH + chunk) * 2 + 0] = accS;
    if (lane == 32) ctotS[(bh * NCH + chunk) * 2 + 1] = accS;
}

// ---------------- K4: chunk-total scans -> per-chunk offsets; zero row CN ------
__global__ __launch_bounds__(64) void offs_kernel(
    const float* __restrict__ ctot, const float* __restrict__ ctotS,
    float* __restrict__ offs, float* __restrict__ offsS,
    float* __restrict__ tbl, float* __restrict__ tblS)
{
    const int bh = blockIdx.x, lane = threadIdx.x, half = lane >> 5;
    float run = 0.f;
    #pragma unroll 8
    for (int ci = 0; ci < NCH; ++ci) {
        const int c = half ? (NCH - 1 - ci) : ci;
        const float t = ctot[(bh * NCH + c) * 64 + lane];
        offs[(bh * (NCH + 1) + c) * 64 + lane] = run;
        run += t;
    }
    offs[(bh * (NCH + 1) + NCH) * 64 + lane] = half ? 0.f : run;
    if (lane == 0 || lane == 32) {
        float runS = 0.f;
        for (int ci = 0; ci < NCH; ++ci) {
            const int c = half ? (NCH - 1 - ci) : ci;
            const float t = ctotS[(bh * NCH + c) * 2 + half];
            offsS[(bh * (NCH + 1) + c) * 2 + half] = runS;
            runS += t;
        }
        offsS[(bh * (NCH + 1) + NCH) * 2 + half] = half ? 0.f : runS;
    }
    tbl[(size_t)(bh * TROWS + CN) * 64 + lane] = 0.f;
    if (lane < 2) tblS[(bh * TROWS + CN) * 2 + lane] = 0.f;
}

// ---------------- K5: binary search + gather + combine ----------------
__global__ __launch_bounds__(256) void out_kernel(
    const float* __restrict__ sarr, const float* __restrict__ dsrt,
    const float* __restrict__ tbl, const float* __restrict__ tblS,
    const float* __restrict__ offs, const float* __restrict__ offsS,
    float* __restrict__ out)
{
    __shared__ float dsS[CN];
    const int bh = blockIdx.x >> 2, it = blockIdx.x & 3, tid = threadIdx.x;
    for (int t = tid; t < CN; t += 256) dsS[t] = dsrt[bh * CN + t];
    __syncthreads();

    const int i = it * 256 + tid;
    const float s = sarr[bh * CN + i];
    const float c1 = __expf(s), c2 = __expf(0.2f * s), thr = -s;

    int lo = 0, hi = CN;
    while (lo < hi) { const int mid = (lo + hi) >> 1; if (dsS[mid] < thr) lo = mid + 1; else hi = mid; }
    const int k = lo, c = k >> 4;              // chunk 0..64 (k==1024 -> 64)

    const float4* trow = (const float4*)(tbl  + (size_t)(bh * TROWS + k) * 64);
    const float4* orow = (const float4*)(offs + (size_t)(bh * (NCH + 1) + c) * 64);
    const float PBs = tblS[(bh * TROWS + k) * 2 + 0] + offsS[(bh * (NCH + 1) + c) * 2 + 0];
    const float Sfs = tblS[(bh * TROWS + k) * 2 + 1] + offsS[(bh * (NCH + 1) + c) * 2 + 1];
    const float inv = 1.0f / (c2 * PBs + c1 * Sfs);

    const int b = bh >> 2, hh = bh & 3;
    float4* o = (float4*)(out + (size_t)(b * CN + i) * CF + hh * 32);
    #pragma unroll
    for (int q = 0; q < 8; ++q) {
        const float4 pb = trow[q],     sf = trow[8 + q];
        const float4 ob = orow[q],     os = orow[8 + q];
        float4 r;
        r.x = (c2 * (pb.x + ob.x) + c1 * (sf.x + os.x)) * inv;
        r.y = (c2 * (pb.y + ob.y) + c1 * (sf.y + os.y)) * inv;
        r.z = (c2 * (pb.z + ob.z) + c1 * (sf.z + os.z)) * inv;
        r.w = (c2 * (pb.w + ob.w) + c1 * (sf.w + os.w)) * inv;
        o[q] = r;
    }
}

extern "C" void kernel_launch(void* const* d_in, const int* in_sizes, int n_in,
                              void* d_out, int out_size, void* d_ws, size_t ws_size,
                              hipStream_t stream) {
    const float* x     = (const float*)d_in[0];
    const float* W     = (const float*)d_in[1];
    const float* a_src = (const float*)d_in[2];
    const float* a_dst = (const float*)d_in[3];
    float* out = (float*)d_out;

    char* ws = (char*)d_ws;
    size_t off = 0;
    float* h_ws  = (float*)(ws + off); off += (size_t)CROWS * CF * 4;              // 4 MB
    float* sarr  = (float*)(ws + off); off += (size_t)CBH * CN * 4;
    float* darr  = (float*)(ws + off); off += (size_t)CBH * CN * 4;
    float* dsrt  = (float*)(ws + off); off += (size_t)CBH * CN * 4;
    int*   perm  = (int*)  (ws + off); off += (size_t)CBH * CN * 4;
    float* tbl   = (float*)(ws + off); off += (size_t)CBH * TROWS * 64 * 4;        // 8.4 MB
    float* tblS  = (float*)(ws + off); off += (size_t)CBH * TROWS * 2 * 4;
    float* ctot  = (float*)(ws + off); off += (size_t)CBH * NCH * 64 * 4;          // 512 KB
    float* ctotS = (float*)(ws + off); off += (size_t)CBH * NCH * 2 * 4;
    float* offsA = (float*)(ws + off); off += (size_t)CBH * (NCH + 1) * 64 * 4;    // 532 KB
    float* offsS = (float*)(ws + off); off += (size_t)CBH * (NCH + 1) * 2 * 4;
    (void)ws_size;

    proj_kernel<<<CROWS / 64, 256, 0, stream>>>(x, W, a_src, a_dst, h_ws, sarr, darr);
    sort_kernel<<<CBH, 1024, 0, stream>>>(darr, dsrt, perm);
    scan_kernel<<<CBH * NCH, 64, 0, stream>>>(h_ws, dsrt, perm, tbl, tblS, ctot, ctotS);
    offs_kernel<<<CBH, 64, 0, stream>>>(ctot, ctotS, offsA, offsS, tbl, tblS);
    out_kernel<<<CBH * 4, 256, 0, stream>>>(sarr, dsrt, tbl, tblS, offsA, offsS, out);
}

// Round 5
// 117.772 us; speedup vs baseline: 1.2886x; 1.1217x over previous
//
#include <hip/hip_runtime.h>

// GAT forward, O(N*HD) via sorted-prefix decomposition. B=8,N=1024,F=128,H=4,HD=32.
// score(i,j)=s_i+d_j; negative iff d_j < -s_i. Per (b,h), sort j by d_j:
//   out[i,:] = (c2*PB[k_i] + c1*SufA[k_i]) / (c2*PBs[k_i] + c1*SufAs[k_i])
// PB: exclusive prefix of e^{0.2d}*h; SufA: inclusive suffix of e^{d}*h;
// k_i = lower_bound(dsrt, -s_i); c1=e^s, c2=e^{0.2s}.
// K1 proj: h=x@W + exact s,d via vs=W@a_src, vd=W@a_dst.
// K2 tail: one block per (b,h): sort+scan+offsets+output, LDS-resident except
//          the 1025x64 local table (L2-resident global scratch).

constexpr int CB  = 8;
constexpr int CN  = 1024;
constexpr int CF  = 128;
constexpr int CH  = 4;
constexpr int CHD = 32;
constexpr int CBH = CB * CH;        // 32
constexpr int CROWS = CB * CN;      // 8192
constexpr int TROWS = CN + 1;       // 1025 table rows (row 1024 = zeros)

// ---------------- K1: projection + exact s/d ----------------
// 512 blocks x 256 thr; block = 16 rows x 128 cols; thread = (row=tid&15, g=tid>>4)
// owning 8 cols. x in LDS stride-132 (2-way max = free); W in LDS 64-k slabs
// (wave-uniform-ish broadcast reads, free). 8 FMA/k/thread -> VALU-bound.
__global__ __launch_bounds__(256) void proj_kernel(
    const float* __restrict__ x, const float* __restrict__ W,
    const float* __restrict__ a_src, const float* __restrict__ a_dst,
    float* __restrict__ h_ws, float* __restrict__ sarr, float* __restrict__ darr)
{
    __shared__ float xs[16 * 132];      // 8.4 KB, padded stride
    __shared__ float wslab[64 * 128];   // 32 KB
    __shared__ float vsld[CH * CF];     // 2 KB
    __shared__ float vdld[CH * CF];     // 2 KB

    const int tid = threadIdx.x, row0 = blockIdx.x * 16;

    // stage x tile: 512 float4, coalesced; padded LDS write (132*4B row = 16B-aligned)
    const float4* x4 = (const float4*)x;
    #pragma unroll
    for (int m = 0; m < 2; ++m) {
        const int idx = m * 256 + tid;              // 0..511
        const int r = idx >> 5, k4 = idx & 31;
        *(float4*)(xs + r * 132 + k4 * 4) = x4[(size_t)row0 * 32 + idx];
    }
    // vs/vd: thread t<128 -> vs row f=t; t>=128 -> vd row f=t-128
    {
        const int f = tid & 127;
        const float* av   = (tid >= 128) ? a_dst : a_src;
        const float* wrow = W + f * CF;
        #pragma unroll
        for (int h = 0; h < CH; ++h) {
            float s = 0.f;
            #pragma unroll 8
            for (int d = 0; d < CHD; ++d) s += wrow[h * 32 + d] * av[h * 32 + d];
            if (tid >= 128) vdld[h * CF + f] = s; else vsld[h * CF + f] = s;
        }
    }

    const int row = tid & 15, g = tid >> 4;         // g: 16 col-groups of 8
    const int head = g >> 2, dd0 = (g & 3) * 8;
    const bool doSD = ((g & 3) == 0);
    float acc[8] = {0.f,0.f,0.f,0.f,0.f,0.f,0.f,0.f};
    float sacc = 0.f, dacc = 0.f;

    const float4* W4 = (const float4*)W;
    for (int slab = 0; slab < 2; ++slab) {
        __syncthreads();                            // xs/vs ready; wslab free to overwrite
        #pragma unroll
        for (int m = 0; m < 8; ++m) {
            const int idx = m * 256 + tid;          // 0..2047
            const int kk = idx >> 5, k4 = idx & 31;
            *(float4*)(wslab + kk * 128 + k4 * 4) = W4[(size_t)(slab * 64 + kk) * 32 + k4];
        }
        __syncthreads();
        #pragma unroll 4
        for (int k4 = 0; k4 < 16; ++k4) {
            const float4 xv = *(const float4*)(xs + row * 132 + slab * 64 + k4 * 4);
            const float xq[4] = {xv.x, xv.y, xv.z, xv.w};
            #pragma unroll
            for (int q = 0; q < 4; ++q) {
                const int kk = k4 * 4 + q;
                const float4 wa = *(const float4*)(wslab + kk * 128 + g * 8);
                const float4 wb = *(const float4*)(wslab + kk * 128 + g * 8 + 4);
                const float xk = xq[q];
                acc[0] += xk * wa.x; acc[1] += xk * wa.y;
                acc[2] += xk * wa.z; acc[3] += xk * wa.w;
                acc[4] += xk * wb.x; acc[5] += xk * wb.y;
                acc[6] += xk * wb.z; acc[7] += xk * wb.w;
                if (doSD) {
                    const int k = slab * 64 + kk;
                    sacc += xk * vsld[head * CF + k];
                    dacc += xk * vdld[head * CF + k];
                }
            }
        }
    }

    const int rowg = row0 + row, b = rowg >> 10, n = rowg & 1023;
    const int bh = b * CH + head;
    float* hp = h_ws + (size_t)(bh * CN + n) * CHD + dd0;
    *(float4*)hp       = make_float4(acc[0], acc[1], acc[2], acc[3]);
    *(float4*)(hp + 4) = make_float4(acc[4], acc[5], acc[6], acc[7]);
    if (doSD) {
        sarr[bh * CN + n] = sacc;
        darr[bh * CN + n] = dacc;
    }
}

// ---------------- K2: fused tail — sort + scan + offsets + output ----------
// 32 blocks (one per bh) x 1024 thr. Local table (1025x64) in global scratch,
// written then gathered by the SAME block (L2-resident; __syncthreads orders it).
__global__ __launch_bounds__(1024) void tail_kernel(
    const float* __restrict__ h_ws, const float* __restrict__ sarr,
    const float* __restrict__ darr, float* __restrict__ tbl_g,
    float* __restrict__ out)
{
    __shared__ float dsS[CN];          // sorted d
    __shared__ int   pjS[CN];          // permutation
    __shared__ float sPB[CN + 1];      // scalar exclusive prefix of e^{0.2d}
    __shared__ float sSF[CN + 1];      // scalar inclusive suffix of e^{d}
    __shared__ float ctF[32 * 32];     // fwd chunk totals [c][dd]
    __shared__ float ctB[32 * 32];     // bwd chunk totals
    __shared__ float ofF[33 * 32];     // fwd chunk offsets
    __shared__ float ofB[33 * 32];     // bwd chunk offsets
    __shared__ float ctSF[32], ctSB[32], ofSF[33], ofSB[33];

    const int bh = blockIdx.x, tid = threadIdx.x;
    float* tbl = tbl_g + (size_t)bh * TROWS * 64;

    // ---- P1: bitonic sort (regs; shuffles j<64, LDS j>=64); (d,p) lex order ----
    float d = darr[bh * CN + tid];
    int   p = tid;
    for (int k = 2; k <= CN; k <<= 1) {
        for (int j = k >> 1; j > 0; j >>= 1) {
            float pd; int pp;
            if (j >= 64) {
                dsS[tid] = d; pjS[tid] = p;
                __syncthreads();
                pd = dsS[tid ^ j]; pp = pjS[tid ^ j];
                __syncthreads();
            } else {
                pd = __shfl_xor(d, j);
                pp = __shfl_xor(p, j);
            }
            const bool up = ((tid & k) == 0), low = ((tid & j) == 0);
            const bool mg = (d > pd) || (d == pd && p > pp);
            if (mg == (low == up)) { d = pd; p = pp; }
        }
    }
    dsS[tid] = d; pjS[tid] = p;
    if (tid == 0) { sPB[CN] = 0.f; sSF[CN] = 0.f; }
    if (tid < 64) tbl[CN * 64 + tid] = 0.f;        // zero virtual row 1024
    __syncthreads();

    // ---- P2: chunk-local scans (chunk = 32 positions); thread = (c, dd) ----
    const int c = tid >> 5, dd = tid & 31, cb = c * 32;
    const float* hb = h_ws + (size_t)bh * CN * CHD;
    {   // forward: exclusive prefix of e^{0.2d}*h
        float accF = 0.f, accS = 0.f;
        #pragma unroll
        for (int bt = 0; bt < 2; ++bt) {
            float hv[16], dv[16];
            #pragma unroll
            for (int t = 0; t < 16; ++t) {
                const int pos = cb + bt * 16 + t;
                hv[t] = hb[(size_t)pjS[pos] * CHD + dd];   // 16 gathers in flight
                dv[t] = dsS[pos];
            }
            #pragma unroll
            for (int t = 0; t < 16; ++t) {
                const int pos = cb + bt * 16 + t;
                const float cf = __expf(0.2f * dv[t]);
                tbl[pos * 64 + dd] = accF;
                if (dd == 0) sPB[pos] = accS;
                accF += cf * hv[t];
                accS += cf;
            }
        }
        ctF[c * 32 + dd] = accF;
        if (dd == 0) ctSF[c] = accS;
    }
    {   // backward: inclusive suffix of e^{d}*h
        float accB = 0.f, accS = 0.f;
        #pragma unroll
        for (int bt = 0; bt < 2; ++bt) {
            float hv[16], dv[16];
            #pragma unroll
            for (int t = 0; t < 16; ++t) {
                const int pos = cb + 31 - (bt * 16 + t);
                hv[t] = hb[(size_t)pjS[pos] * CHD + dd];
                dv[t] = dsS[pos];
            }
            #pragma unroll
            for (int t = 0; t < 16; ++t) {
                const int pos = cb + 31 - (bt * 16 + t);
                const float cf = __expf(dv[t]);
                accB += cf * hv[t];
                accS += cf;
                tbl[pos * 64 + 32 + dd] = accB;
                if (dd == 0) sSF[pos] = accS;
            }
        }
        ctB[c * 32 + dd] = accB;
        if (dd == 0) ctSB[c] = accS;
    }
    __syncthreads();

    // ---- P3: chunk offsets (serial over <=31 chunk totals, LDS) ----
    {
        float run = 0.f;
        for (int c2 = 0; c2 < c; ++c2) run += ctF[c2 * 32 + dd];
        ofF[c * 32 + dd] = run;
        if (c == 31) ofF[32 * 32 + dd] = run + ctF[31 * 32 + dd];
        float run2 = 0.f;
        for (int c2 = c + 1; c2 < 32; ++c2) run2 += ctB[c2 * 32 + dd];
        ofB[c * 32 + dd] = run2;
        if (c == 0) ofB[32 * 32 + dd] = 0.f;
        if (dd == 0) {
            float rs = 0.f;
            for (int c2 = 0; c2 < c; ++c2) rs += ctSF[c2];
            ofSF[c] = rs;
            if (c == 31) ofSF[32] = rs + ctSF[31];
            float rs2 = 0.f;
            for (int c2 = c + 1; c2 < 32; ++c2) rs2 += ctSB[c2];
            ofSB[c] = rs2;
            if (c == 0) ofSB[32] = 0.f;
        }
    }
    __syncthreads();

    // ---- P4: per-row binary search + gather + combine ----
    {
        const int i = tid;
        const float s = sarr[bh * CN + i];
        const float c1 = __expf(s), c2v = __expf(0.2f * s), thr = -s;
        int lo = 0, hi = CN;
        while (lo < hi) { const int mid = (lo + hi) >> 1; if (dsS[mid] < thr) lo = mid + 1; else hi = mid; }
        const int k = lo, kc = k >> 5;             // 0..32 (k==1024 -> 32)

        const float PBs = sPB[k] + ofSF[kc];
        const float SFs = sSF[k] + ofSB[kc];
        const float inv = 1.0f / (c2v * PBs + c1 * SFs);

        const float4* tr = (const float4*)(tbl + (size_t)k * 64);
        const int b = bh >> 2, hh = bh & 3;
        float4* o = (float4*)(out + (size_t)(b * CN + i) * CF + hh * 32);
        #pragma unroll
        for (int q = 0; q < 8; ++q) {
            const float4 pb = tr[q], sf = tr[8 + q];
            const float4 oa = *(const float4*)(&ofF[kc * 32 + q * 4]);
            const float4 ob = *(const float4*)(&ofB[kc * 32 + q * 4]);
            float4 r;
            r.x = (c2v * (pb.x + oa.x) + c1 * (sf.x + ob.x)) * inv;
            r.y = (c2v * (pb.y + oa.y) + c1 * (sf.y + ob.y)) * inv;
            r.z = (c2v * (pb.z + oa.z) + c1 * (sf.z + ob.z)) * inv;
            r.w = (c2v * (pb.w + oa.w) + c1 * (sf.w + ob.w)) * inv;
            o[q] = r;
        }
    }
}

extern "C" void kernel_launch(void* const* d_in, const int* in_sizes, int n_in,
                              void* d_out, int out_size, void* d_ws, size_t ws_size,
                              hipStream_t stream) {
    const float* x     = (const float*)d_in[0];
    const float* W     = (const float*)d_in[1];
    const float* a_src = (const float*)d_in[2];
    const float* a_dst = (const float*)d_in[3];
    float* out = (float*)d_out;

    char* ws = (char*)d_ws;
    size_t off = 0;
    float* h_ws = (float*)(ws + off); off += (size_t)CROWS * CF * 4;        // 4 MB
    float* sarr = (float*)(ws + off); off += (size_t)CBH * CN * 4;          // 128 KB
    float* darr = (float*)(ws + off); off += (size_t)CBH * CN * 4;          // 128 KB
    float* tblg = (float*)(ws + off); off += (size_t)CBH * TROWS * 64 * 4;  // 8.4 MB
    (void)ws_size;

    proj_kernel<<<CROWS / 16, 256, 0, stream>>>(x, W, a_src, a_dst, h_ws, sarr, darr);
    tail_kernel<<<CBH, 1024, 0, stream>>>(h_ws, sarr, darr, tblg, out);
}